// Round 14
// baseline (350.712 us; speedup 1.0000x reference)
//
#include <hip/hip_runtime.h>

// Problem constants (shapes fixed by the reference).
#define FIN   128
#define FHID  128
#define FOUT  64
#define FFC   256
#define CHUNK 4096     // edges per binA block
#define SORT_CAP 10240 // max edges per bucket for LDS sort (mean 8163, std ~90)

typedef __attribute__((ext_vector_type(8))) short          bf16x8;
typedef __attribute__((ext_vector_type(4))) float          f32x4;
typedef __attribute__((ext_vector_type(8))) unsigned short u16x8;

// ---------------------------------------------------------------------------
// bf16 helpers (raw ushort, RNE rounding)
static __device__ __forceinline__ unsigned short f2bf(float f) {
    unsigned int u = __float_as_uint(f);
    u = (u + 0x7fffu + ((u >> 16) & 1u)) >> 16;
    return (unsigned short)u;
}
static __device__ __forceinline__ float bf2f(unsigned short s) {
    return __uint_as_float(((unsigned int)s) << 16);
}

// ---------------------------------------------------------------------------
// Fused converts: threads [0,73728) transpose+convert the four weights;
// threads [73728, 73728+n4) convert x (one float4 group each).
__global__ void cvt_all_kernel(
    const float* __restrict__ x, const float* __restrict__ W1,
    const float* __restrict__ W2, const float* __restrict__ Wf1,
    const float* __restrict__ Wf2,
    unsigned short* __restrict__ xbf, unsigned short* __restrict__ w1t,
    unsigned short* __restrict__ w2t, unsigned short* __restrict__ wf1t,
    unsigned short* __restrict__ wf2t, long n4)
{
    long i = (long)blockIdx.x * blockDim.x + threadIdx.x;
    if (i < 16384) {                       // W1 [128,128]
        int k = (int)i >> 7, n = (int)i & 127;
        w1t[n * 128 + k] = f2bf(W1[i]);
    } else if (i < 24576) {                // W2 [128,64]
        int j = (int)i - 16384; int k = j >> 6, n = j & 63;
        w2t[n * 128 + k] = f2bf(W2[j]);
    } else if (i < 57344) {                // Wf1 [128,256]
        int j = (int)i - 24576; int k = j >> 8, n = j & 255;
        wf1t[n * 128 + k] = f2bf(Wf1[j]);
    } else if (i < 73728) {                // Wf2 [256,64]
        int j = (int)i - 57344; int k = j >> 6, n = j & 63;
        wf2t[n * 256 + k] = f2bf(Wf2[j]);
    } else if (i < 73728 + n4) {           // x, float4 group
        long j = i - 73728;
        float4 v = ((const float4*)x)[j];
        ushort4 o = make_ushort4(f2bf(v.x), f2bf(v.y), f2bf(v.z), f2bf(v.w));
        ((ushort4*)xbf)[j] = o;
    }
}

// ---------------------------------------------------------------------------
// Bucketed CSR build. Bucket b = dst >> 8 (256 nodes per bucket).
__global__ __launch_bounds__(256) void hist_kernel(
    const int* __restrict__ dst, int* __restrict__ bhist, int E, int NBK)
{
    __shared__ int h[256];
    int t = threadIdx.x;
    h[t] = 0;
    __syncthreads();
    for (int e = blockIdx.x * blockDim.x + t; e < E; e += gridDim.x * blockDim.x)
        atomicAdd(&h[dst[e] >> 8], 1);
    __syncthreads();
    if (t < NBK && h[t]) atomicAdd(&bhist[t], h[t]);
}

__global__ __launch_bounds__(256) void bscan_kernel(
    const int* __restrict__ bhist, int* __restrict__ bbase,
    int* __restrict__ bcur, int NBK)
{
    __shared__ int tmp[256];
    int t = threadIdx.x;
    int v = (t < NBK) ? bhist[t] : 0;
    tmp[t] = v;
    __syncthreads();
    int acc = v;
    for (int off = 1; off < 256; off <<= 1) {
        int a = (t >= off) ? tmp[t - off] : 0;
        __syncthreads();
        acc += a; tmp[t] = acc;
        __syncthreads();
    }
    if (t < NBK) { bbase[t] = acc - v; bcur[t] = acc - v; }
}

__global__ __launch_bounds__(256) void binA_kernel(
    const int* __restrict__ src, const int* __restrict__ dst,
    int* __restrict__ bcur, uint2* __restrict__ ebuf, int E, int NBK)
{
    __shared__ int hist[256];
    __shared__ int rstart[256];
    __shared__ int lcur[256];
    int t = threadIdx.x;
    hist[t] = 0; lcur[t] = 0;
    __syncthreads();
    int e0 = blockIdx.x * CHUNK;
    int e1 = min(e0 + CHUNK, E);
    for (int e = e0 + t; e < e1; e += 256)
        atomicAdd(&hist[dst[e] >> 8], 1);
    __syncthreads();
    if (t < NBK && hist[t] > 0) rstart[t] = atomicAdd(&bcur[t], hist[t]);
    __syncthreads();
    for (int e = e0 + t; e < e1; e += 256) {
        int s = src[e], d = dst[e];
        int b = d >> 8;
        int pos = atomicAdd(&lcur[b], 1);
        ebuf[rstart[b] + pos] = make_uint2((unsigned)s, (unsigned)d);
    }
}

// Phase B: one block per bucket. Node counts -> dinv + rp; parallel counting
// sort by src>>8 (coarse src order = gather locality); drain into col in
// barriered windows; write xs = dinv*x rows (row-major).
__global__ __launch_bounds__(256) void binB_kernel(
    const uint2* __restrict__ ebuf, const int* __restrict__ bbase,
    const int* __restrict__ bhist, int* __restrict__ rp,
    int* __restrict__ col, float* __restrict__ dinv,
    const unsigned short* __restrict__ xbf, unsigned short* __restrict__ xs,
    int N)
{
    __shared__ int cnt[256];
    __shared__ int tmp[256];
    __shared__ int ccur[256];
    __shared__ int scur[256];          // src-bucket cursors
    __shared__ float sdinv[256];
    __shared__ unsigned int skey[SORT_CAP];
    int b = blockIdx.x;
    int t = threadIdx.x;
    int base = bbase[b];
    int ne = bhist[b];
    cnt[t] = 0; scur[t] = 0;
    __syncthreads();
    for (int e = t; e < ne; e += 256) {
        uint2 ed = ebuf[base + e];
        atomicAdd(&cnt[ed.y & 255], 1);
        atomicAdd(&scur[ed.x >> 8], 1);
    }
    __syncthreads();
    int node = b * 256 + t;
    int c = cnt[t];
    float di = rsqrtf((float)c + 1.0f);
    sdinv[t] = di;
    if (node < N) dinv[node] = di;
    tmp[t] = c;
    __syncthreads();
    int acc = c;
    for (int off = 1; off < 256; off <<= 1) {
        int a = (t >= off) ? tmp[t - off] : 0;
        __syncthreads();
        acc += a; tmp[t] = acc;
        __syncthreads();
    }
    if (node < N) rp[node] = base + acc;    // inclusive end of node's segment
    ccur[t] = base + acc - c;               // start cursor
    __syncthreads();
    int sv = scur[t];
    tmp[t] = sv;
    __syncthreads();
    int sacc = sv;
    for (int off = 1; off < 256; off <<= 1) {
        int a = (t >= off) ? tmp[t - off] : 0;
        __syncthreads();
        sacc += a; tmp[t] = sacc;
        __syncthreads();
    }
    scur[t] = sacc - sv;
    __syncthreads();
    if (ne <= SORT_CAP) {
        for (int e = t; e < ne; e += 256) {
            uint2 ed = ebuf[base + e];
            int pos = atomicAdd(&scur[ed.x >> 8], 1);
            skey[pos] = (ed.x << 8) | (ed.y & 255);
        }
        __syncthreads();
        for (int w = 0; w < ne; w += 256) {
            int e = w + t;
            if (e < ne) {
                unsigned int k = skey[e];
                int pos = atomicAdd(&ccur[k & 255], 1);
                col[pos] = (int)(k >> 8);
            }
            __syncthreads();
        }
    } else {
        for (int e = t; e < ne; e += 256) {
            uint2 ed = ebuf[base + e];
            int pos = atomicAdd(&ccur[ed.y & 255], 1);
            col[pos] = (int)ed.x;
        }
        __syncthreads();
    }
    int node0 = b * 256;
    #pragma unroll
    for (int it = 0; it < 16; it++) {
        int nl = it * 16 + (t >> 4);
        int gn = node0 + nl;
        if (gn >= N) continue;
        float d2 = sdinv[nl];
        int fo = (t & 15) << 3;
        u16x8 v = *(const u16x8*)(xbf + (size_t)gn * FIN + fo);
        u16x8 o;
        #pragma unroll
        for (int j = 0; j < 8; j++) o[j] = f2bf(d2 * bf2f(v[j]));
        *(u16x8*)(xs + (size_t)gn * FIN + fo) = o;
    }
}

// ---------------------------------------------------------------------------
// MFMA bf16 GEMM, B staged in LDS (all waves share it), LDS-bounce epilogue.
template <int CF, int KK, int CBF, int RELU, int SCALE>
__global__ __launch_bounds__(256) void mfma_gemm(
    const unsigned short* __restrict__ A, const unsigned short* __restrict__ BT,
    const float* __restrict__ bias, const float* __restrict__ rowscale,
    void* __restrict__ Cv, int M, int Ncol)
{
    constexpr int ESZ  = CBF ? 2 : 4;
    constexpr int ROWB = CF * 16 * ESZ + 16;     // padded epilogue row bytes
    constexpr int LROW = KK + 8;                 // padded LDS B row (ushorts)
    __shared__ __align__(16) unsigned short blds[CF * 16 * LROW];

    const int tid = threadIdx.x;
    const int col0 = blockIdx.x * (CF * 16);

    {
        const unsigned short* bsrc = BT + (size_t)col0 * KK;
        constexpr int TOT = CF * 16 * KK / 8;
        #pragma unroll 2
        for (int i = tid; i < TOT; i += 256) {
            int idx = i * 8;
            int r = idx / KK;
            int o = idx - r * KK;
            *(u16x8*)&blds[r * LROW + o] = *(const u16x8*)(bsrc + idx);
        }
    }
    __syncthreads();

    const int lane = tid & 63;
    const int wave = tid >> 6;
    const int m = lane & 15;
    const int q = lane >> 4;
    const int rowbase = blockIdx.y * 64 + wave * 16;
    const int row = rowbase + m;

    f32x4 acc[CF] = {};
    const unsigned short* arow = A + (size_t)row * KK + q * 8;
    const unsigned short* lb = blds + m * LROW + q * 8;

    for (int k0 = 0; k0 < KK; k0 += 32) {
        bf16x8 a = {};
        if (row < M) a = *(const bf16x8*)(arow + k0);
        #pragma unroll
        for (int c = 0; c < CF; c++) {
            bf16x8 b = *(const bf16x8*)(lb + c * 16 * LROW + k0);
            acc[c] = __builtin_amdgcn_mfma_f32_16x16x32_bf16(a, b, acc[c], 0, 0, 0);
        }
    }

    float rs[4];
    #pragma unroll
    for (int r = 0; r < 4; r++) {
        int gr = rowbase + q * 4 + r;
        rs[r] = (SCALE && gr < M) ? rowscale[gr] : 1.0f;
    }

    __syncthreads();   // all waves done reading blds -> safe to alias
    unsigned char* wbase = (unsigned char*)blds + wave * 16 * ROWB;
    #pragma unroll
    for (int c = 0; c < CF; c++) {
        int lc = c * 16 + m;
        float bv = bias ? bias[col0 + lc] : 0.0f;
        #pragma unroll
        for (int r = 0; r < 4; r++) {
            float v = acc[c][r] + bv;
            if (SCALE) v *= rs[r];
            if (RELU) v = fmaxf(v, 0.f);
            if (CBF) ((unsigned short*)(wbase + (q * 4 + r) * ROWB))[lc] = f2bf(v);
            else     ((float*)(wbase + (q * 4 + r) * ROWB))[lc] = v;
        }
    }
    constexpr int LPR = CF * ESZ;        // lanes per row (16B each)
    constexpr int RPP = 64 / LPR;        // rows per pass
    constexpr int NP  = 16 / RPP;        // passes
    #pragma unroll
    for (int p = 0; p < NP; p++) {
        int r2 = p * RPP + lane / LPR;
        int bo = (lane % LPR) * 16;
        int gr = rowbase + r2;
        if (gr < M) {
            uint4 v = *(const uint4*)(wbase + r2 * ROWB + bo);
            *(uint4*)((unsigned char*)Cv + (size_t)gr * Ncol * ESZ
                      + (size_t)col0 * ESZ + bo) = v;
        }
    }
}

// ---------------------------------------------------------------------------
// CSR pull, F=128, pre-scaled rows, src-sorted lists, 8x edge unroll:
// aggx[i] = di*(xs[i] + sum_s xs[s]).  16 lanes/node, 16B/lane.
__global__ __launch_bounds__(256) void pull1_kernel(
    const unsigned short* __restrict__ xs, const int* __restrict__ rp,
    const int* __restrict__ col, const float* __restrict__ dinv,
    unsigned short* __restrict__ aggx, int N)
{
    int tid = threadIdx.x;
    int node = blockIdx.x * 16 + (tid >> 4);
    if (node >= N) return;
    int f0 = (tid & 15) << 3;
    const unsigned short* base = xs + f0;
    u16x8 own = *(const u16x8*)(base + (size_t)node * FIN);
    float acc[8];
    #pragma unroll
    for (int j = 0; j < 8; j++) acc[j] = bf2f(own[j]);
    int e = node ? rp[node - 1] : 0;
    int end = rp[node];
    for (; e + 8 <= end; e += 8) {
        int s0 = col[e],     s1 = col[e + 1], s2 = col[e + 2], s3 = col[e + 3];
        int s4 = col[e + 4], s5 = col[e + 5], s6 = col[e + 6], s7 = col[e + 7];
        u16x8 v0 = *(const u16x8*)(base + (size_t)s0 * FIN);
        u16x8 v1 = *(const u16x8*)(base + (size_t)s1 * FIN);
        u16x8 v2 = *(const u16x8*)(base + (size_t)s2 * FIN);
        u16x8 v3 = *(const u16x8*)(base + (size_t)s3 * FIN);
        u16x8 v4 = *(const u16x8*)(base + (size_t)s4 * FIN);
        u16x8 v5 = *(const u16x8*)(base + (size_t)s5 * FIN);
        u16x8 v6 = *(const u16x8*)(base + (size_t)s6 * FIN);
        u16x8 v7 = *(const u16x8*)(base + (size_t)s7 * FIN);
        #pragma unroll
        for (int j = 0; j < 8; j++)
            acc[j] += ((bf2f(v0[j]) + bf2f(v1[j])) + (bf2f(v2[j]) + bf2f(v3[j])))
                    + ((bf2f(v4[j]) + bf2f(v5[j])) + (bf2f(v6[j]) + bf2f(v7[j])));
    }
    for (; e + 4 <= end; e += 4) {
        int s0 = col[e], s1 = col[e + 1], s2 = col[e + 2], s3 = col[e + 3];
        u16x8 v0 = *(const u16x8*)(base + (size_t)s0 * FIN);
        u16x8 v1 = *(const u16x8*)(base + (size_t)s1 * FIN);
        u16x8 v2 = *(const u16x8*)(base + (size_t)s2 * FIN);
        u16x8 v3 = *(const u16x8*)(base + (size_t)s3 * FIN);
        #pragma unroll
        for (int j = 0; j < 8; j++)
            acc[j] += (bf2f(v0[j]) + bf2f(v1[j])) + (bf2f(v2[j]) + bf2f(v3[j]));
    }
    for (; e < end; e++) {
        u16x8 v = *(const u16x8*)(base + (size_t)col[e] * FIN);
        #pragma unroll
        for (int j = 0; j < 8; j++) acc[j] += bf2f(v[j]);
    }
    float di = dinv[node];
    u16x8 o;
    #pragma unroll
    for (int j = 0; j < 8; j++) o[j] = f2bf(di * acc[j]);
    *(u16x8*)(aggx + (size_t)node * FIN + f0) = o;
}

// CSR pull, F=64, pre-scaled rows, fused bias+blend, 8x unroll; bf16 z out.
__global__ __launch_bounds__(256) void pull2_kernel(
    const unsigned short* __restrict__ t2s, const int* __restrict__ rp,
    const int* __restrict__ col, const float* __restrict__ dinv,
    const float* __restrict__ xfc, const float* __restrict__ b2,
    unsigned short* __restrict__ zbf, int N)
{
    int tid = threadIdx.x;
    int node = blockIdx.x * 32 + (tid >> 3);
    if (node >= N) return;
    int f0 = (tid & 7) << 3;
    const unsigned short* base = t2s + f0;
    u16x8 own = *(const u16x8*)(base + (size_t)node * FOUT);
    float acc[8];
    #pragma unroll
    for (int j = 0; j < 8; j++) acc[j] = bf2f(own[j]);
    int e = node ? rp[node - 1] : 0;
    int end = rp[node];
    for (; e + 8 <= end; e += 8) {
        int s0 = col[e],     s1 = col[e + 1], s2 = col[e + 2], s3 = col[e + 3];
        int s4 = col[e + 4], s5 = col[e + 5], s6 = col[e + 6], s7 = col[e + 7];
        u16x8 v0 = *(const u16x8*)(base + (size_t)s0 * FOUT);
        u16x8 v1 = *(const u16x8*)(base + (size_t)s1 * FOUT);
        u16x8 v2 = *(const u16x8*)(base + (size_t)s2 * FOUT);
        u16x8 v3 = *(const u16x8*)(base + (size_t)s3 * FOUT);
        u16x8 v4 = *(const u16x8*)(base + (size_t)s4 * FOUT);
        u16x8 v5 = *(const u16x8*)(base + (size_t)s5 * FOUT);
        u16x8 v6 = *(const u16x8*)(base + (size_t)s6 * FOUT);
        u16x8 v7 = *(const u16x8*)(base + (size_t)s7 * FOUT);
        #pragma unroll
        for (int j = 0; j < 8; j++)
            acc[j] += ((bf2f(v0[j]) + bf2f(v1[j])) + (bf2f(v2[j]) + bf2f(v3[j])))
                    + ((bf2f(v4[j]) + bf2f(v5[j])) + (bf2f(v6[j]) + bf2f(v7[j])));
    }
    for (; e + 4 <= end; e += 4) {
        int s0 = col[e], s1 = col[e + 1], s2 = col[e + 2], s3 = col[e + 3];
        u16x8 v0 = *(const u16x8*)(base + (size_t)s0 * FOUT);
        u16x8 v1 = *(const u16x8*)(base + (size_t)s1 * FOUT);
        u16x8 v2 = *(const u16x8*)(base + (size_t)s2 * FOUT);
        u16x8 v3 = *(const u16x8*)(base + (size_t)s3 * FOUT);
        #pragma unroll
        for (int j = 0; j < 8; j++)
            acc[j] += (bf2f(v0[j]) + bf2f(v1[j])) + (bf2f(v2[j]) + bf2f(v3[j]));
    }
    for (; e < end; e++) {
        u16x8 v = *(const u16x8*)(base + (size_t)col[e] * FOUT);
        #pragma unroll
        for (int j = 0; j < 8; j++) acc[j] += bf2f(v[j]);
    }
    float di = dinv[node];
    float4 x0 = *(const float4*)(xfc + (size_t)node * FOUT + f0);
    float4 x1 = *(const float4*)(xfc + (size_t)node * FOUT + f0 + 4);
    float4 bb0 = *(const float4*)(b2 + f0);
    float4 bb1 = *(const float4*)(b2 + f0 + 4);
    float xf[8] = { x0.x, x0.y, x0.z, x0.w, x1.x, x1.y, x1.z, x1.w };
    float bv[8] = { bb0.x, bb0.y, bb0.z, bb0.w, bb1.x, bb1.y, bb1.z, bb1.w };
    u16x8 o;
    #pragma unroll
    for (int j = 0; j < 8; j++)
        o[j] = f2bf(0.5f * (di * acc[j] + bv[j]) + 0.5f * xf[j]);
    *(u16x8*)(zbf + (size_t)node * FOUT + f0) = o;
}

// 2 queries per 8-lane group (4 row loads in flight); 16B bf16 per lane.
__global__ void decode_kernel(
    const unsigned short* __restrict__ zbf, const int* __restrict__ eli,
    float* __restrict__ out, int Q)
{
    int tid = blockIdx.x * blockDim.x + threadIdx.x;
    int g = tid >> 3;
    int lane = tid & 7;
    int q0 = g * 2;
    if (q0 >= Q) return;
    int q1 = q0 + 1;
    bool has1 = q1 < Q;
    int a0 = eli[q0];
    int b0 = eli[Q + q0];
    int a1 = has1 ? eli[q1] : a0;
    int b1 = has1 ? eli[Q + q1] : b0;
    const unsigned short* base = zbf + lane * 8;
    u16x8 va0 = *(const u16x8*)(base + (size_t)a0 * FOUT);
    u16x8 vb0 = *(const u16x8*)(base + (size_t)b0 * FOUT);
    u16x8 va1 = *(const u16x8*)(base + (size_t)a1 * FOUT);
    u16x8 vb1 = *(const u16x8*)(base + (size_t)b1 * FOUT);
    float s0 = 0.f, s1 = 0.f;
    #pragma unroll
    for (int j = 0; j < 8; j++) {
        s0 += bf2f(va0[j]) * bf2f(vb0[j]);
        s1 += bf2f(va1[j]) * bf2f(vb1[j]);
    }
    s0 += __shfl_down(s0, 4, 8);
    s0 += __shfl_down(s0, 2, 8);
    s0 += __shfl_down(s0, 1, 8);
    s1 += __shfl_down(s1, 4, 8);
    s1 += __shfl_down(s1, 2, 8);
    s1 += __shfl_down(s1, 1, 8);
    if (lane == 0) {
        out[q0] = s0;
        if (has1) out[q1] = s1;
    }
}

// ---------------------------------------------------------------------------
extern "C" void kernel_launch(void* const* d_in, const int* in_sizes, int n_in,
                              void* d_out, int out_size, void* d_ws, size_t ws_size,
                              hipStream_t stream)
{
    const float* x   = (const float*)d_in[0];
    const int*   ei  = (const int*)  d_in[1];
    const int*   eli = (const int*)  d_in[2];
    const float* W1  = (const float*)d_in[3];
    const float* b1  = (const float*)d_in[4];
    const float* W2  = (const float*)d_in[5];
    const float* b2  = (const float*)d_in[6];
    const float* Wf1 = (const float*)d_in[7];
    const float* bf1 = (const float*)d_in[8];
    const float* Wf2 = (const float*)d_in[9];
    const float* bf2 = (const float*)d_in[10];
    float* out = (float*)d_out;

    const int N = in_sizes[0] / FIN;       // 50000
    const int E = in_sizes[1] / 2;         // 1600000
    const int Q = in_sizes[2] / 2;         // 500000
    const int* src = ei;
    const int* dst = ei + E;
    const int NBK = (N + 255) >> 8;        // 196 buckets

    // Workspace layout (bytes; 16B-aligned). Peak ~58 MB.
    char* p = (char*)d_ws;
    float* dinv  = (float*)p;            p += (size_t)N * 4;
    int*   rp    = (int*)p;              p += (size_t)(N + 4) * 4;
    int*   bhist = (int*)p;              p += 1024;
    int*   bbase = (int*)p;              p += 1024;
    int*   bcur  = (int*)p;              p += 1024;
    int*   col   = (int*)p;              p += (size_t)E * 4;
    unsigned short* xbf  = (unsigned short*)p; p += (size_t)N * FIN * 2;
    unsigned short* w1t  = (unsigned short*)p; p += FIN * FHID * 2;
    unsigned short* w2t  = (unsigned short*)p; p += FHID * FOUT * 2;
    unsigned short* wf1t = (unsigned short*)p; p += FIN * FFC * 2;
    unsigned short* wf2t = (unsigned short*)p; p += FFC * FOUT * 2;
    float* xfc = (float*)p;              p += (size_t)N * FOUT * 4;
    char*  S   = p;
    unsigned short* f1   = (unsigned short*)S;
    unsigned short* xs   = (unsigned short*)S;
    uint2*          ebuf = (uint2*)(S + (size_t)N * FIN * 2);
    unsigned short* aggx = (unsigned short*)(S + (size_t)N * FIN * 2);
    unsigned short* h1   = (unsigned short*)S;
    unsigned short* t2s  = (unsigned short*)(S + (size_t)N * FIN * 2);
    unsigned short* zbf  = (unsigned short*)(S + (size_t)N * FIN * 2
                                               + (size_t)N * FOUT * 2);

    const int TB = 256;

    // --- converts (one kernel) ---
    {
        long n4 = (long)N * FIN / 4;
        long tot = 73728 + n4;
        cvt_all_kernel<<<(int)((tot + TB - 1) / TB), TB, 0, stream>>>(
            x, W1, W2, Wf1, Wf2, xbf, w1t, w2t, wf1t, wf2t, n4);
    }

    // --- FC path: FC1 (col-split, LDS-staged B), FC2 ---
    {
        dim3 g(2, (N + 63) / 64);
        mfma_gemm<8, 128, 1, 1, 0><<<g, TB, 0, stream>>>(xbf, wf1t, bf1, nullptr, f1, N, FFC);
    }
    {
        dim3 g(1, (N + 63) / 64);
        mfma_gemm<4, 256, 0, 0, 0><<<g, TB, 0, stream>>>(f1, wf2t, bf2, nullptr, xfc, N, FOUT);
    }

    // --- bucketed CSR build (+ coarse src-sort + fused dinv & xs scaling) ---
    hipMemsetAsync(bhist, 0, 1024, stream);
    hist_kernel<<<1024, TB, 0, stream>>>(dst, bhist, E, NBK);
    bscan_kernel<<<1, TB, 0, stream>>>(bhist, bbase, bcur, NBK);
    binA_kernel<<<(E + CHUNK - 1) / CHUNK, TB, 0, stream>>>(src, dst, bcur, ebuf, E, NBK);
    binB_kernel<<<NBK, TB, 0, stream>>>(ebuf, bbase, bhist, rp, col, dinv, xbf, xs, N);

    // --- GCN layer 1: aggx = dinv*(xs + sum xs); h1 = relu(aggx@W1+b1) ---
    pull1_kernel<<<(N + 15) / 16, TB, 0, stream>>>(xs, rp, col, dinv, aggx, N);
    {
        dim3 g(1, (N + 63) / 64);
        mfma_gemm<8, 128, 1, 1, 0><<<g, TB, 0, stream>>>(aggx, w1t, b1, nullptr, h1, N, FHID);
    }

    // --- GCN layer 2: t2s = dinv*(h1@W2) [bf16]; z = 0.5*(dinv*agg+b2)+0.5*xfc ---
    {
        dim3 g(1, (N + 63) / 64);
        mfma_gemm<4, 128, 1, 0, 1><<<g, TB, 0, stream>>>(h1, w2t, nullptr, dinv, t2s, N, FOUT);
    }
    pull2_kernel<<<(N + 31) / 32, TB, 0, stream>>>(t2s, rp, col, dinv, xfc, b2, zbf, N);

    // --- decode: 2 queries per 8-lane group ---
    {
        long total = (long)((Q + 1) / 2) * 8;
        decode_kernel<<<(int)((total + TB - 1) / TB), TB, 0, stream>>>(zbf, eli, out, Q);
    }
}

// Round 15
// 318.041 us; speedup vs baseline: 1.1027x; 1.1027x over previous
//
#include <hip/hip_runtime.h>

// Problem constants (shapes fixed by the reference).
#define FIN   128
#define FHID  128
#define FOUT  64
#define FFC   256
#define CHUNK 4096     // edges per binA block
#define SORT_CAP 10240 // max edges per bucket for LDS sort (mean 8163, std ~90)

typedef __attribute__((ext_vector_type(8))) short          bf16x8;
typedef __attribute__((ext_vector_type(4))) float          f32x4;
typedef __attribute__((ext_vector_type(2))) float          f32x2;
typedef __attribute__((ext_vector_type(8))) unsigned short u16x8;

// ---------------------------------------------------------------------------
// bf16 helpers (raw ushort, RNE rounding)
static __device__ __forceinline__ unsigned short f2bf(float f) {
    unsigned int u = __float_as_uint(f);
    u = (u + 0x7fffu + ((u >> 16) & 1u)) >> 16;
    return (unsigned short)u;
}
static __device__ __forceinline__ float bf2f(unsigned short s) {
    return __uint_as_float(((unsigned int)s) << 16);
}

// ---------------------------------------------------------------------------
// Fused converts: threads [0,73728) transpose+convert the four weights;
// threads [73728, 73728+n4) convert x (one float4 group each).
__global__ void cvt_all_kernel(
    const float* __restrict__ x, const float* __restrict__ W1,
    const float* __restrict__ W2, const float* __restrict__ Wf1,
    const float* __restrict__ Wf2,
    unsigned short* __restrict__ xbf, unsigned short* __restrict__ w1t,
    unsigned short* __restrict__ w2t, unsigned short* __restrict__ wf1t,
    unsigned short* __restrict__ wf2t, long n4)
{
    long i = (long)blockIdx.x * blockDim.x + threadIdx.x;
    if (i < 16384) {                       // W1 [128,128]
        int k = (int)i >> 7, n = (int)i & 127;
        w1t[n * 128 + k] = f2bf(W1[i]);
    } else if (i < 24576) {                // W2 [128,64]
        int j = (int)i - 16384; int k = j >> 6, n = j & 63;
        w2t[n * 128 + k] = f2bf(W2[j]);
    } else if (i < 57344) {                // Wf1 [128,256]
        int j = (int)i - 24576; int k = j >> 8, n = j & 255;
        wf1t[n * 128 + k] = f2bf(Wf1[j]);
    } else if (i < 73728) {                // Wf2 [256,64]
        int j = (int)i - 57344; int k = j >> 6, n = j & 63;
        wf2t[n * 256 + k] = f2bf(Wf2[j]);
    } else if (i < 73728 + n4) {           // x, float4 group
        long j = i - 73728;
        float4 v = ((const float4*)x)[j];
        ushort4 o = make_ushort4(f2bf(v.x), f2bf(v.y), f2bf(v.z), f2bf(v.w));
        ((ushort4*)xbf)[j] = o;
    }
}

// ---------------------------------------------------------------------------
// Bucketed CSR build. Bucket b = dst >> 8 (256 nodes per bucket).
__global__ __launch_bounds__(256) void hist_kernel(
    const int* __restrict__ dst, int* __restrict__ bhist, int E, int NBK)
{
    __shared__ int h[256];
    int t = threadIdx.x;
    h[t] = 0;
    __syncthreads();
    for (int e = blockIdx.x * blockDim.x + t; e < E; e += gridDim.x * blockDim.x)
        atomicAdd(&h[dst[e] >> 8], 1);
    __syncthreads();
    if (t < NBK && h[t]) atomicAdd(&bhist[t], h[t]);
}

__global__ __launch_bounds__(256) void bscan_kernel(
    const int* __restrict__ bhist, int* __restrict__ bbase,
    int* __restrict__ bcur, int NBK)
{
    __shared__ int tmp[256];
    int t = threadIdx.x;
    int v = (t < NBK) ? bhist[t] : 0;
    tmp[t] = v;
    __syncthreads();
    int acc = v;
    for (int off = 1; off < 256; off <<= 1) {
        int a = (t >= off) ? tmp[t - off] : 0;
        __syncthreads();
        acc += a; tmp[t] = acc;
        __syncthreads();
    }
    if (t < NBK) { bbase[t] = acc - v; bcur[t] = acc - v; }
}

__global__ __launch_bounds__(256) void binA_kernel(
    const int* __restrict__ src, const int* __restrict__ dst,
    int* __restrict__ bcur, uint2* __restrict__ ebuf, int E, int NBK)
{
    __shared__ int hist[256];
    __shared__ int rstart[256];
    __shared__ int lcur[256];
    int t = threadIdx.x;
    hist[t] = 0; lcur[t] = 0;
    __syncthreads();
    int e0 = blockIdx.x * CHUNK;
    int e1 = min(e0 + CHUNK, E);
    for (int e = e0 + t; e < e1; e += 256)
        atomicAdd(&hist[dst[e] >> 8], 1);
    __syncthreads();
    if (t < NBK && hist[t] > 0) rstart[t] = atomicAdd(&bcur[t], hist[t]);
    __syncthreads();
    for (int e = e0 + t; e < e1; e += 256) {
        int s = src[e], d = dst[e];
        int b = d >> 8;
        int pos = atomicAdd(&lcur[b], 1);
        ebuf[rstart[b] + pos] = make_uint2((unsigned)s, (unsigned)d);
    }
}

// Phase B: one block per bucket. Node counts -> dinv + rp; parallel counting
// sort by src>>8 (coarse src order = gather locality); drain into col in
// barriered windows; write xs = dinv*x rows as fp8 e4m3 (128 B rows).
__global__ __launch_bounds__(256) void binB_kernel(
    const uint2* __restrict__ ebuf, const int* __restrict__ bbase,
    const int* __restrict__ bhist, int* __restrict__ rp,
    int* __restrict__ col, float* __restrict__ dinv,
    const unsigned short* __restrict__ xbf, unsigned char* __restrict__ xs,
    int N)
{
    __shared__ int cnt[256];
    __shared__ int tmp[256];
    __shared__ int ccur[256];
    __shared__ int scur[256];          // src-bucket cursors
    __shared__ float sdinv[256];
    __shared__ unsigned int skey[SORT_CAP];
    int b = blockIdx.x;
    int t = threadIdx.x;
    int base = bbase[b];
    int ne = bhist[b];
    cnt[t] = 0; scur[t] = 0;
    __syncthreads();
    for (int e = t; e < ne; e += 256) {
        uint2 ed = ebuf[base + e];
        atomicAdd(&cnt[ed.y & 255], 1);
        atomicAdd(&scur[ed.x >> 8], 1);
    }
    __syncthreads();
    int node = b * 256 + t;
    int c = cnt[t];
    float di = rsqrtf((float)c + 1.0f);
    sdinv[t] = di;
    if (node < N) dinv[node] = di;
    tmp[t] = c;
    __syncthreads();
    int acc = c;
    for (int off = 1; off < 256; off <<= 1) {
        int a = (t >= off) ? tmp[t - off] : 0;
        __syncthreads();
        acc += a; tmp[t] = acc;
        __syncthreads();
    }
    if (node < N) rp[node] = base + acc;    // inclusive end of node's segment
    ccur[t] = base + acc - c;               // start cursor
    __syncthreads();
    int sv = scur[t];
    tmp[t] = sv;
    __syncthreads();
    int sacc = sv;
    for (int off = 1; off < 256; off <<= 1) {
        int a = (t >= off) ? tmp[t - off] : 0;
        __syncthreads();
        sacc += a; tmp[t] = sacc;
        __syncthreads();
    }
    scur[t] = sacc - sv;
    __syncthreads();
    if (ne <= SORT_CAP) {
        for (int e = t; e < ne; e += 256) {
            uint2 ed = ebuf[base + e];
            int pos = atomicAdd(&scur[ed.x >> 8], 1);
            skey[pos] = (ed.x << 8) | (ed.y & 255);
        }
        __syncthreads();
        for (int w = 0; w < ne; w += 256) {
            int e = w + t;
            if (e < ne) {
                unsigned int k = skey[e];
                int pos = atomicAdd(&ccur[k & 255], 1);
                col[pos] = (int)(k >> 8);
            }
            __syncthreads();
        }
    } else {
        for (int e = t; e < ne; e += 256) {
            uint2 ed = ebuf[base + e];
            int pos = atomicAdd(&ccur[ed.y & 255], 1);
            col[pos] = (int)ed.x;
        }
        __syncthreads();
    }
    // fused: xs rows (fp8 e4m3) for this bucket; 16 lanes/node x 8 feats (8B)
    int node0 = b * 256;
    #pragma unroll
    for (int it = 0; it < 16; it++) {
        int nl = it * 16 + (t >> 4);
        int gn = node0 + nl;
        if (gn >= N) continue;
        float d2 = sdinv[nl];
        int fo = (t & 15) << 3;
        u16x8 v = *(const u16x8*)(xbf + (size_t)gn * FIN + fo);
        float f[8];
        #pragma unroll
        for (int j = 0; j < 8; j++) f[j] = d2 * bf2f(v[j]);
        unsigned int w0 = 0, w1 = 0;
        w0 = __builtin_amdgcn_cvt_pk_fp8_f32(f[0], f[1], w0, false);
        w0 = __builtin_amdgcn_cvt_pk_fp8_f32(f[2], f[3], w0, true);
        w1 = __builtin_amdgcn_cvt_pk_fp8_f32(f[4], f[5], w1, false);
        w1 = __builtin_amdgcn_cvt_pk_fp8_f32(f[6], f[7], w1, true);
        *(uint2*)(xs + (size_t)gn * 128 + fo) = make_uint2(w0, w1);
    }
}

// ---------------------------------------------------------------------------
// MFMA bf16 GEMM, B staged in LDS (all waves share it), LDS-bounce epilogue.
template <int CF, int KK, int CBF, int RELU, int SCALE>
__global__ __launch_bounds__(256) void mfma_gemm(
    const unsigned short* __restrict__ A, const unsigned short* __restrict__ BT,
    const float* __restrict__ bias, const float* __restrict__ rowscale,
    void* __restrict__ Cv, int M, int Ncol)
{
    constexpr int ESZ  = CBF ? 2 : 4;
    constexpr int ROWB = CF * 16 * ESZ + 16;     // padded epilogue row bytes
    constexpr int LROW = KK + 8;                 // padded LDS B row (ushorts)
    __shared__ __align__(16) unsigned short blds[CF * 16 * LROW];

    const int tid = threadIdx.x;
    const int col0 = blockIdx.x * (CF * 16);

    {
        const unsigned short* bsrc = BT + (size_t)col0 * KK;
        constexpr int TOT = CF * 16 * KK / 8;
        #pragma unroll 2
        for (int i = tid; i < TOT; i += 256) {
            int idx = i * 8;
            int r = idx / KK;
            int o = idx - r * KK;
            *(u16x8*)&blds[r * LROW + o] = *(const u16x8*)(bsrc + idx);
        }
    }
    __syncthreads();

    const int lane = tid & 63;
    const int wave = tid >> 6;
    const int m = lane & 15;
    const int q = lane >> 4;
    const int rowbase = blockIdx.y * 64 + wave * 16;
    const int row = rowbase + m;

    f32x4 acc[CF] = {};
    const unsigned short* arow = A + (size_t)row * KK + q * 8;
    const unsigned short* lb = blds + m * LROW + q * 8;

    for (int k0 = 0; k0 < KK; k0 += 32) {
        bf16x8 a = {};
        if (row < M) a = *(const bf16x8*)(arow + k0);
        #pragma unroll
        for (int c = 0; c < CF; c++) {
            bf16x8 b = *(const bf16x8*)(lb + c * 16 * LROW + k0);
            acc[c] = __builtin_amdgcn_mfma_f32_16x16x32_bf16(a, b, acc[c], 0, 0, 0);
        }
    }

    float rs[4];
    #pragma unroll
    for (int r = 0; r < 4; r++) {
        int gr = rowbase + q * 4 + r;
        rs[r] = (SCALE && gr < M) ? rowscale[gr] : 1.0f;
    }

    __syncthreads();   // all waves done reading blds -> safe to alias
    unsigned char* wbase = (unsigned char*)blds + wave * 16 * ROWB;
    #pragma unroll
    for (int c = 0; c < CF; c++) {
        int lc = c * 16 + m;
        float bv = bias ? bias[col0 + lc] : 0.0f;
        #pragma unroll
        for (int r = 0; r < 4; r++) {
            float v = acc[c][r] + bv;
            if (SCALE) v *= rs[r];
            if (RELU) v = fmaxf(v, 0.f);
            if (CBF) ((unsigned short*)(wbase + (q * 4 + r) * ROWB))[lc] = f2bf(v);
            else     ((float*)(wbase + (q * 4 + r) * ROWB))[lc] = v;
        }
    }
    constexpr int LPR = CF * ESZ;        // lanes per row (16B each)
    constexpr int RPP = 64 / LPR;        // rows per pass
    constexpr int NP  = 16 / RPP;        // passes
    #pragma unroll
    for (int p = 0; p < NP; p++) {
        int r2 = p * RPP + lane / LPR;
        int bo = (lane % LPR) * 16;
        int gr = rowbase + r2;
        if (gr < M) {
            uint4 v = *(const uint4*)(wbase + r2 * ROWB + bo);
            *(uint4*)((unsigned char*)Cv + (size_t)gr * Ncol * ESZ
                      + (size_t)col0 * ESZ + bo) = v;
        }
    }
}

// ---------------------------------------------------------------------------
// CSR pull, F=128, fp8 e4m3 table (128 B rows), src-sorted lists, 4x unroll:
// aggx[i] = di*(xs[i] + sum_s xs[s]).  16 lanes/node, 8 B (8 feats)/lane.
__global__ __launch_bounds__(256) void pull1_kernel(
    const unsigned char* __restrict__ xs, const int* __restrict__ rp,
    const int* __restrict__ col, const float* __restrict__ dinv,
    unsigned short* __restrict__ aggx, int N)
{
    int tid = threadIdx.x;
    int node = blockIdx.x * 16 + (tid >> 4);
    if (node >= N) return;
    int f0 = (tid & 15) << 3;      // feature offset (elems == bytes for fp8)
    const unsigned char* base = xs + f0;
    float acc[8] = {};
    {
        uint2 g = *(const uint2*)(base + (size_t)node * 128);
        f32x2 p0 = __builtin_amdgcn_cvt_pk_f32_fp8(g.x, false);
        f32x2 p1 = __builtin_amdgcn_cvt_pk_f32_fp8(g.x, true);
        f32x2 p2 = __builtin_amdgcn_cvt_pk_f32_fp8(g.y, false);
        f32x2 p3 = __builtin_amdgcn_cvt_pk_f32_fp8(g.y, true);
        acc[0] = p0.x; acc[1] = p0.y; acc[2] = p1.x; acc[3] = p1.y;
        acc[4] = p2.x; acc[5] = p2.y; acc[6] = p3.x; acc[7] = p3.y;
    }
    int e = node ? rp[node - 1] : 0;
    int end = rp[node];
    for (; e + 4 <= end; e += 4) {
        int s0 = col[e], s1 = col[e + 1], s2 = col[e + 2], s3 = col[e + 3];
        uint2 g0 = *(const uint2*)(base + (size_t)s0 * 128);
        uint2 g1 = *(const uint2*)(base + (size_t)s1 * 128);
        uint2 g2 = *(const uint2*)(base + (size_t)s2 * 128);
        uint2 g3 = *(const uint2*)(base + (size_t)s3 * 128);
        #pragma unroll
        for (int u = 0; u < 4; u++) {
            uint2 g = (u == 0) ? g0 : (u == 1) ? g1 : (u == 2) ? g2 : g3;
            f32x2 p0 = __builtin_amdgcn_cvt_pk_f32_fp8(g.x, false);
            f32x2 p1 = __builtin_amdgcn_cvt_pk_f32_fp8(g.x, true);
            f32x2 p2 = __builtin_amdgcn_cvt_pk_f32_fp8(g.y, false);
            f32x2 p3 = __builtin_amdgcn_cvt_pk_f32_fp8(g.y, true);
            acc[0] += p0.x; acc[1] += p0.y; acc[2] += p1.x; acc[3] += p1.y;
            acc[4] += p2.x; acc[5] += p2.y; acc[6] += p3.x; acc[7] += p3.y;
        }
    }
    for (; e < end; e++) {
        uint2 g = *(const uint2*)(base + (size_t)col[e] * 128);
        f32x2 p0 = __builtin_amdgcn_cvt_pk_f32_fp8(g.x, false);
        f32x2 p1 = __builtin_amdgcn_cvt_pk_f32_fp8(g.x, true);
        f32x2 p2 = __builtin_amdgcn_cvt_pk_f32_fp8(g.y, false);
        f32x2 p3 = __builtin_amdgcn_cvt_pk_f32_fp8(g.y, true);
        acc[0] += p0.x; acc[1] += p0.y; acc[2] += p1.x; acc[3] += p1.y;
        acc[4] += p2.x; acc[5] += p2.y; acc[6] += p3.x; acc[7] += p3.y;
    }
    float di = dinv[node];
    u16x8 o;
    #pragma unroll
    for (int j = 0; j < 8; j++) o[j] = f2bf(di * acc[j]);
    *(u16x8*)(aggx + (size_t)node * FIN + f0) = o;
}

// CSR pull, F=64, bf16 pre-scaled rows, fused bias+blend, 4x unroll.
__global__ __launch_bounds__(256) void pull2_kernel(
    const unsigned short* __restrict__ t2s, const int* __restrict__ rp,
    const int* __restrict__ col, const float* __restrict__ dinv,
    const float* __restrict__ xfc, const float* __restrict__ b2,
    unsigned short* __restrict__ zbf, int N)
{
    int tid = threadIdx.x;
    int node = blockIdx.x * 32 + (tid >> 3);
    if (node >= N) return;
    int f0 = (tid & 7) << 3;
    const unsigned short* base = t2s + f0;
    u16x8 own = *(const u16x8*)(base + (size_t)node * FOUT);
    float acc[8];
    #pragma unroll
    for (int j = 0; j < 8; j++) acc[j] = bf2f(own[j]);
    int e = node ? rp[node - 1] : 0;
    int end = rp[node];
    for (; e + 4 <= end; e += 4) {
        int s0 = col[e], s1 = col[e + 1], s2 = col[e + 2], s3 = col[e + 3];
        u16x8 v0 = *(const u16x8*)(base + (size_t)s0 * FOUT);
        u16x8 v1 = *(const u16x8*)(base + (size_t)s1 * FOUT);
        u16x8 v2 = *(const u16x8*)(base + (size_t)s2 * FOUT);
        u16x8 v3 = *(const u16x8*)(base + (size_t)s3 * FOUT);
        #pragma unroll
        for (int j = 0; j < 8; j++)
            acc[j] += (bf2f(v0[j]) + bf2f(v1[j])) + (bf2f(v2[j]) + bf2f(v3[j]));
    }
    for (; e < end; e++) {
        u16x8 v = *(const u16x8*)(base + (size_t)col[e] * FOUT);
        #pragma unroll
        for (int j = 0; j < 8; j++) acc[j] += bf2f(v[j]);
    }
    float di = dinv[node];
    float4 x0 = *(const float4*)(xfc + (size_t)node * FOUT + f0);
    float4 x1 = *(const float4*)(xfc + (size_t)node * FOUT + f0 + 4);
    float4 bb0 = *(const float4*)(b2 + f0);
    float4 bb1 = *(const float4*)(b2 + f0 + 4);
    float xf[8] = { x0.x, x0.y, x0.z, x0.w, x1.x, x1.y, x1.z, x1.w };
    float bv[8] = { bb0.x, bb0.y, bb0.z, bb0.w, bb1.x, bb1.y, bb1.z, bb1.w };
    u16x8 o;
    #pragma unroll
    for (int j = 0; j < 8; j++)
        o[j] = f2bf(0.5f * (di * acc[j] + bv[j]) + 0.5f * xf[j]);
    *(u16x8*)(zbf + (size_t)node * FOUT + f0) = o;
}

// out[q] = dot(z[a], z[b]) over 64 dims; 8 threads/query, 16B bf16 each.
__global__ void decode_kernel(
    const unsigned short* __restrict__ zbf, const int* __restrict__ eli,
    float* __restrict__ out, int Q)
{
    int tid = blockIdx.x * blockDim.x + threadIdx.x;
    int q = tid >> 3;
    if (q >= Q) return;
    int lane = tid & 7;
    int a = eli[q];
    int b = eli[Q + q];
    u16x8 va = *(const u16x8*)(zbf + (size_t)a * FOUT + lane * 8);
    u16x8 vb = *(const u16x8*)(zbf + (size_t)b * FOUT + lane * 8);
    float s = 0.f;
    #pragma unroll
    for (int j = 0; j < 8; j++) s += bf2f(va[j]) * bf2f(vb[j]);
    s += __shfl_down(s, 4, 8);
    s += __shfl_down(s, 2, 8);
    s += __shfl_down(s, 1, 8);
    if (lane == 0) out[q] = s;
}

// ---------------------------------------------------------------------------
extern "C" void kernel_launch(void* const* d_in, const int* in_sizes, int n_in,
                              void* d_out, int out_size, void* d_ws, size_t ws_size,
                              hipStream_t stream)
{
    const float* x   = (const float*)d_in[0];
    const int*   ei  = (const int*)  d_in[1];
    const int*   eli = (const int*)  d_in[2];
    const float* W1  = (const float*)d_in[3];
    const float* b1  = (const float*)d_in[4];
    const float* W2  = (const float*)d_in[5];
    const float* b2  = (const float*)d_in[6];
    const float* Wf1 = (const float*)d_in[7];
    const float* bf1 = (const float*)d_in[8];
    const float* Wf2 = (const float*)d_in[9];
    const float* bf2 = (const float*)d_in[10];
    float* out = (float*)d_out;

    const int N = in_sizes[0] / FIN;       // 50000
    const int E = in_sizes[1] / 2;         // 1600000
    const int Q = in_sizes[2] / 2;         // 500000
    const int* src = ei;
    const int* dst = ei + E;
    const int NBK = (N + 255) >> 8;        // 196 buckets

    // Workspace layout (bytes; 16B-aligned). Peak ~58 MB.
    char* p = (char*)d_ws;
    float* dinv  = (float*)p;            p += (size_t)N * 4;
    int*   rp    = (int*)p;              p += (size_t)(N + 4) * 4;
    int*   bhist = (int*)p;              p += 1024;
    int*   bbase = (int*)p;              p += 1024;
    int*   bcur  = (int*)p;              p += 1024;
    int*   col   = (int*)p;              p += (size_t)E * 4;
    unsigned short* xbf  = (unsigned short*)p; p += (size_t)N * FIN * 2;
    unsigned short* w1t  = (unsigned short*)p; p += FIN * FHID * 2;
    unsigned short* w2t  = (unsigned short*)p; p += FHID * FOUT * 2;
    unsigned short* wf1t = (unsigned short*)p; p += FIN * FFC * 2;
    unsigned short* wf2t = (unsigned short*)p; p += FFC * FOUT * 2;
    float* xfc = (float*)p;              p += (size_t)N * FOUT * 4;
    char*  S   = p;
    unsigned short* f1   = (unsigned short*)S;
    unsigned char*  xs   = (unsigned char*)S;                           // [N][128] fp8
    uint2*          ebuf = (uint2*)(S + (size_t)N * FIN * 2);
    unsigned short* aggx = (unsigned short*)(S + (size_t)N * FIN * 2);
    unsigned short* h1   = (unsigned short*)S;
    unsigned short* t2s  = (unsigned short*)(S + (size_t)N * FIN * 2);
    unsigned short* zbf  = (unsigned short*)(S + (size_t)N * FIN * 2
                                               + (size_t)N * FOUT * 2);

    const int TB = 256;

    // --- converts (one kernel) ---
    {
        long n4 = (long)N * FIN / 4;
        long tot = 73728 + n4;
        cvt_all_kernel<<<(int)((tot + TB - 1) / TB), TB, 0, stream>>>(
            x, W1, W2, Wf1, Wf2, xbf, w1t, w2t, wf1t, wf2t, n4);
    }

    // --- FC path: FC1 (col-split, LDS-staged B), FC2 ---
    {
        dim3 g(2, (N + 63) / 64);
        mfma_gemm<8, 128, 1, 1, 0><<<g, TB, 0, stream>>>(xbf, wf1t, bf1, nullptr, f1, N, FFC);
    }
    {
        dim3 g(1, (N + 63) / 64);
        mfma_gemm<4, 256, 0, 0, 0><<<g, TB, 0, stream>>>(f1, wf2t, bf2, nullptr, xfc, N, FOUT);
    }

    // --- bucketed CSR build (+ coarse src-sort + fused dinv & fp8 xs) ---
    hipMemsetAsync(bhist, 0, 1024, stream);
    hist_kernel<<<1024, TB, 0, stream>>>(dst, bhist, E, NBK);
    bscan_kernel<<<1, TB, 0, stream>>>(bhist, bbase, bcur, NBK);
    binA_kernel<<<(E + CHUNK - 1) / CHUNK, TB, 0, stream>>>(src, dst, bcur, ebuf, E, NBK);
    binB_kernel<<<NBK, TB, 0, stream>>>(ebuf, bbase, bhist, rp, col, dinv, xbf, xs, N);

    // --- GCN layer 1: aggx = dinv*(xs + sum xs) [fp8 gather]; h1 = relu(aggx@W1+b1) ---
    pull1_kernel<<<(N + 15) / 16, TB, 0, stream>>>(xs, rp, col, dinv, aggx, N);
    {
        dim3 g(1, (N + 63) / 64);
        mfma_gemm<8, 128, 1, 1, 0><<<g, TB, 0, stream>>>(aggx, w1t, b1, nullptr, h1, N, FHID);
    }

    // --- GCN layer 2: t2s = dinv*(h1@W2) [bf16]; z = 0.5*(dinv*agg+b2)+0.5*xfc ---
    {
        dim3 g(1, (N + 63) / 64);
        mfma_gemm<4, 128, 1, 0, 1><<<g, TB, 0, stream>>>(h1, w2t, nullptr, dinv, t2s, N, FOUT);
    }
    pull2_kernel<<<(N + 31) / 32, TB, 0, stream>>>(t2s, rp, col, dinv, xfc, b2, zbf, N);

    // --- decode ---
    {
        long total = (long)Q * 8;
        decode_kernel<<<(total + TB - 1) / TB, TB, 0, stream>>>(zbf, eli, out, Q);
    }
}